// Round 2
// baseline (198.630 us; speedup 1.0000x reference)
//
#include <hip/hip_runtime.h>
#include <hip/hip_bf16.h>

// All tensors are float32 (verified R2/R3: runtime dtype probe took the f32
// branch; bf16 interpretation NaN'd in R1/R4). Output float32.
//
// k_rnn floor note (R6-R12): seven structural variants of the 64-step RNN
// tie at 42-47 us. Kept verbatim.
//
// R1 post-mortem: 256-block/256-thread fused attn collapsed occupancy to
// 4 waves/CU (10%) and the es[k*20+qh] writes were 8-way bank-conflicted
// (1M conflicts). R2: 512 threads/block (8 waves/CU), es qq-rotation
// swizzle (max 2-way), q read via wave-uniform scalar loads (no LDS),
// k-range split across wave halves with LDS partial combine.

#define NB 16
#define NL 256
#define NLQ 64
#define NDIN 32
#define NET 128
#define NH 4
#define NETK 32

// Padded LDS layout for h/tmp in k_rnn (R8: conflicts -> 0).
#define HPAD 136
#define PAD(i) ((i) + 4 * ((i) >> 6))

// es row stride (floats): 16 values [qq-group rotated by (k>>3)&3][h] + pad 4.
// Write: float2 at col ((qq+rot)&3)*4 + hp*2 -> banks spread, max 2-way.
// Read: one aligned float4 at col ((qq+rot)&3)*4 -> h=0..3 directly.
#define ESS 20
#define ORP 132

// ---------------------------------------------------------------------------
// Kernel 1: time embedding + K/Q projection, 8 rows per block.
// grid = 512 (k-rows) + 8 (q-rows) = 520 blocks, 128 threads.
// ---------------------------------------------------------------------------
__global__ __launch_bounds__(128) void k_embed_proj(
    const float* __restrict__ ts, const float* __restrict__ query,
    const float* __restrict__ w_lin, const float* __restrict__ b_lin,
    const float* __restrict__ w_per, const float* __restrict__ b_per,
    const float* __restrict__ Wk, const float* __restrict__ bk,
    const float* __restrict__ Wq, const float* __restrict__ bq,
    float* __restrict__ kproj, float* __restrict__ qproj) {
  __shared__ float emb[8 * NET];
  int g = blockIdx.x;
  int j = threadIdx.x;
  bool isQ = (g >= 512);
  int base = (isQ ? g - 512 : g) * 8;
  float wl_ = w_lin[0], bl_ = b_lin[0];
  float wp = (j > 0) ? w_per[j - 1] : 0.f;
  float bp = (j > 0) ? b_per[j - 1] : 0.f;
#pragma unroll
  for (int rr = 0; rr < 8; rr++) {
    float t = isQ ? query[base + rr] : ts[base + rr];
    emb[rr * NET + j] = (j == 0) ? (t * wl_ + bl_) : sinf(t * wp + bp);
  }
  __syncthreads();
  const float* W = isQ ? Wq : Wk;
  float bias = isQ ? bq[j] : bk[j];
  float acc[8];
#pragma unroll
  for (int rr = 0; rr < 8; rr++) acc[rr] = bias;
#pragma unroll 4
  for (int i = 0; i < NET; i++) {
    float wv = W[i * NET + j];
#pragma unroll
    for (int rr = 0; rr < 8; rr++) acc[rr] += emb[rr * NET + i] * wv;
  }
  float* dst = isQ ? qproj : kproj;
#pragma unroll
  for (int rr = 0; rr < 8; rr++) dst[(size_t)(base + rr) * NET + j] = acc[rr];
}

// ---------------------------------------------------------------------------
// Kernel 2: fused attention (all 4 heads) + Wo/Wih projection.
// block = (b, qgroup of 4). grid = 256 blocks, 512 threads (8 waves/CU).
// LDS ~59 KB. Masked softmax collapses per-channel:
// att_x = sum(e*m*x)/sum(e*m); all-masked channel => mean(x), att_m = 0.
// ---------------------------------------------------------------------------
__global__ __launch_bounds__(512, 2) void k_attn_fused(
    const float* __restrict__ x, const float* __restrict__ mask,
    const float* __restrict__ qproj, const float* __restrict__ kproj,
    const float* __restrict__ Wo, const float* __restrict__ bo,
    const float* __restrict__ Wih, const float* __restrict__ bih,
    const float* __restrict__ bhh, float* __restrict__ XW) {
  const float SC = 0.17677669529663687f;  // 1/sqrt(32)
  int blk = blockIdx.x;
  int qg = blk & 15;
  int b  = blk >> 4;
  int t  = threadIdx.x;

  __shared__ __align__(16) float xs[NL * NDIN];  // 32 KB
  __shared__ unsigned mb[NL];                    // 1 KB
  __shared__ __align__(16) float es[NL * ESS];   // 20 KB (aliased by part[])
  __shared__ float arow[4 * 256];                // 4 KB
  __shared__ float orow[4 * ORP];                // ~2 KB
  float* part = es;  // 128*9 floats, valid only after phase-B barrier

  // stage x slice (coalesced float4, 512 threads x 4)
  {
    const float4* src = (const float4*)(x + (size_t)b * NL * NDIN);
    float4* dst = (float4*)xs;
#pragma unroll
    for (int u = 0; u < 4; u++) dst[t + 512 * u] = src[t + 512 * u];
  }
  // mask bits, one row per thread (t < 256)
  if (t < NL) {
    const float4* mr4 = (const float4*)(mask + (size_t)(b * NL + t) * NDIN);
    unsigned bits = 0;
#pragma unroll
    for (int u = 0; u < 8; u++) {
      float4 m = mr4[u];
      bits |= (m.x != 0.f ? 1u : 0u) << (4 * u);
      bits |= (m.y != 0.f ? 1u : 0u) << (4 * u + 1);
      bits |= (m.z != 0.f ? 1u : 0u) << (4 * u + 2);
      bits |= (m.w != 0.f ? 1u : 0u) << (4 * u + 3);
    }
    mb[t] = bits;
  }
  __syncthreads();

  // phase A: scores -> exp. thread = (k = t&255, hpair = t>>8).
  // q read directly from qproj: address is wave-uniform -> scalar loads.
  {
    int k  = t & 255;
    int hp = t >> 8;  // handles h = 2hp, 2hp+1
    float kr[64];
    const float4* kp =
        (const float4*)(kproj + (size_t)(b * NL + k) * NET + hp * 64);
#pragma unroll
    for (int i = 0; i < 16; i++) {
      float4 v = kp[i];
      kr[4 * i] = v.x; kr[4 * i + 1] = v.y;
      kr[4 * i + 2] = v.z; kr[4 * i + 3] = v.w;
    }
    int rot = (k >> 3) & 3;
#pragma unroll
    for (int qq = 0; qq < 4; qq++) {
      const float* qrow = qproj + (size_t)(qg * 4 + qq) * NET + hp * 64;
      float s0 = 0.f, s1 = 0.f;
#pragma unroll
      for (int i = 0; i < 32; i++) {
        s0 += qrow[i] * kr[i];
        s1 += qrow[32 + i] * kr[32 + i];
      }
      float2 ev = make_float2(__expf(s0 * SC), __expf(s1 * SC));
      int col = ((qq + rot) & 3) * 4 + hp * 2;
      *(float2*)&es[k * ESS + col] = ev;
    }
  }
  __syncthreads();

  // phase B: wave w = (qq = w&3, khalf = w>>2); lane = (s = l&1, c = l>>1).
  // Each thread: 64 k-iters over [khalf*128 + s*64, +64).
  float den[NH], num[NH], sumx;
  int qq, c, s, kh;
  {
    int w = t >> 6, lane = t & 63;
    qq = w & 3; kh = w >> 2;
    s = lane & 1; c = lane >> 1;
    int k0 = kh * 128 + s * 64;
#pragma unroll
    for (int h = 0; h < NH; h++) { den[h] = 0.f; num[h] = 0.f; }
    sumx = 0.f;
#pragma unroll 4
    for (int kk = 0; kk < 64; kk++) {
      int k = k0 + kk;
      float xv = xs[k * NDIN + c];
      float mv = ((mb[k] >> c) & 1u) ? 1.f : 0.f;
      int col = ((qq + ((k >> 3) & 3)) & 3) * 4;
      float4 e4 = *(const float4*)(es + k * ESS + col);
      sumx += xv;
      float e0 = e4.x * mv, e1 = e4.y * mv, e2 = e4.z * mv, e3 = e4.w * mv;
      den[0] += e0; num[0] += e0 * xv;
      den[1] += e1; num[1] += e1 * xv;
      den[2] += e2; num[2] += e2 * xv;
      den[3] += e3; num[3] += e3 * xv;
    }
    sumx += __shfl_xor(sumx, 1, 64);
#pragma unroll
    for (int h = 0; h < NH; h++) {
      den[h] += __shfl_xor(den[h], 1, 64);
      num[h] += __shfl_xor(num[h], 1, 64);
    }
  }
  __syncthreads();  // all waves done reading es; part[] may now alias it

  // upper k-half waves publish partials: part[(qq*32+c)*9 + {den0..3,num0..3,sumx}]
  if (kh == 1 && s == 0) {
    float* p = part + (qq * 32 + c) * 9;
#pragma unroll
    for (int h = 0; h < NH; h++) { p[h] = den[h]; p[4 + h] = num[h]; }
    p[8] = sumx;
  }
  __syncthreads();

  // lower k-half waves combine + finalize into arow
  if (kh == 0 && s == 0) {
    const float* p = part + (qq * 32 + c) * 9;
    float sx = sumx + p[8];
    float meanx = sx * (1.f / 256.f);
#pragma unroll
    for (int h = 0; h < NH; h++) {
      float d = den[h] + p[h];
      float n = num[h] + p[4 + h];
      bool any = (d > 0.f);
      arow[qq * 256 + h * 64 + c]      = any ? (n / d) : meanx;
      arow[qq * 256 + h * 64 + 32 + c] = any ? 1.f : 0.f;
    }
  }
  __syncthreads();

  // epilogue 1: out[qq][j] = arow[qq] . Wo[:,j] + bo[j]. thread = (j, qq).
  {
    int j = t & 127;
    int q4 = t >> 7;  // wave-uniform
    float o = bo[j];
#pragma unroll 4
    for (int u = 0; u < 256; u++) o += arow[q4 * 256 + u] * Wo[(size_t)u * NET + j];
    orow[q4 * ORP + j] = o;
  }
  __syncthreads();

  // epilogue 2: XW[q][j] = orow[qq] . Wih[:,j] + bih[j] + bhh[j]
  {
    int j = t & 127;
    int q4 = t >> 7;
    float a = bih[j] + bhh[j];
#pragma unroll 4
    for (int e = 0; e < NET; e++) a += orow[q4 * ORP + e] * Wih[(size_t)e * NET + j];
    int q = qg * 4 + q4;
    XW[(size_t)(b * NLQ + q) * NET + j] = a;
  }
}

// ---------------------------------------------------------------------------
// helper: dst[PAD(j)] = b[j] + sum_i src[i] * W[i*128+j], split-2 over s.
// ---------------------------------------------------------------------------
__device__ __forceinline__ void layer128(const float* src_lds,
                                         const float* __restrict__ W,
                                         const float* __restrict__ bvec,
                                         float* dst_lds, int j, int s) {
  const float4* h4 = (const float4*)(src_lds + s * 68);
  float a0 = 0.f, a1 = 0.f, a2 = 0.f, a3 = 0.f;
#pragma unroll
  for (int i = 0; i < 16; i++) {
    float4 hv = h4[i];
    int base = (s * 64 + 4 * i) * NET + j;
    a0 += hv.x * W[base];
    a1 += hv.y * W[base + NET];
    a2 += hv.z * W[base + 2 * NET];
    a3 += hv.w * W[base + 3 * NET];
  }
  float acc = (a0 + a1) + (a2 + a3);
  acc += __shfl_xor(acc, 1, 64);
  if (s == 0) dst_lds[PAD(j)] = acc + bvec[j];
}

// ---------------------------------------------------------------------------
// Kernel 3: sequential RNN (64 steps) + regressor. grid = 16, 256 threads.
// Kept verbatim (measured floor ~42 us).
// ---------------------------------------------------------------------------
__global__ __launch_bounds__(256, 1) void k_rnn(
    const float* __restrict__ XW, const float* __restrict__ Whh,
    const float* __restrict__ r1w, const float* __restrict__ r1b,
    const float* __restrict__ r2w, const float* __restrict__ r2b,
    const float* __restrict__ r3w, const float* __restrict__ r3b,
    const float* __restrict__ r4w, const float* __restrict__ r4b,
    float* __restrict__ out) {
  int b = blockIdx.x;
  int tid = threadIdx.x;
  int s = tid & 1;
  int j = tid >> 1;
  __shared__ float xwl[NLQ * NET];  // 32 KB, staged once
  __shared__ float hb[2][HPAD];
  __shared__ float tmp[HPAD];

  {
    const float4* src = (const float4*)(XW + (size_t)b * NLQ * NET);
    float4* dst = (float4*)xwl;
#pragma unroll
    for (int u = 0; u < 8; u++) dst[tid + 256 * u] = src[tid + 256 * u];
  }
  float w[64];
#pragma unroll
  for (int i = 0; i < 64; i++) w[i] = Whh[(s * 64 + i) * NET + j];

  if (tid < 128) hb[0][PAD(tid)] = 0.f;
  __syncthreads();

  for (int t = 0; t < NLQ; t++) {
    float xwv = xwl[t * NET + j];
    const float4* h4 = (const float4*)&hb[t & 1][s * 68];
    float a0 = 0.f, a1 = 0.f, a2 = 0.f, a3 = 0.f;
#pragma unroll
    for (int i = 0; i < 16; i++) {
      float4 hv = h4[i];
      a0 += hv.x * w[4 * i];
      a1 += hv.y * w[4 * i + 1];
      a2 += hv.z * w[4 * i + 2];
      a3 += hv.w * w[4 * i + 3];
    }
    float acc = (a0 + a1) + (a2 + a3);
    acc += __shfl_xor(acc, 1, 64);
    if (s == 0) {
      float z = acc + xwv;
      float e2 = __expf(2.f * z);
      hb[(t + 1) & 1][PAD(j)] = 1.f - 2.f / (e2 + 1.f);  // tanh(z)
    }
    __syncthreads();
  }

  layer128(hb[0], r1w, r1b, tmp, j, s);
  __syncthreads();
  layer128(tmp, r2w, r2b, hb[1], j, s);
  __syncthreads();
  layer128(hb[1], r3w, r3b, hb[0], j, s);
  __syncthreads();
  if (tid < 64) {
    int jj = tid >> 3, p = tid & 7;
    float y = 0.f;
#pragma unroll
    for (int i = 0; i < 16; i++) {
      int ii = p * 16 + i;
      y += hb[0][PAD(ii)] * r4w[ii * 8 + jj];
    }
    y += __shfl_xor(y, 1, 64);
    y += __shfl_xor(y, 2, 64);
    y += __shfl_xor(y, 4, 64);
    if (p == 0) out[b * 8 + jj] = y + r4b[jj];
  }
}

// ---------------------------------------------------------------------------
extern "C" void kernel_launch(void* const* d_in, const int* in_sizes, int n_in,
                              void* d_out, int out_size, void* d_ws, size_t ws_size,
                              hipStream_t stream) {
  const float* x     = (const float*)d_in[0];
  const float* ts    = (const float*)d_in[1];
  const float* mask  = (const float*)d_in[2];
  const float* query = (const float*)d_in[3];
  const float* w_lin = (const float*)d_in[4];
  const float* b_lin = (const float*)d_in[5];
  const float* w_per = (const float*)d_in[6];
  const float* b_per = (const float*)d_in[7];
  const float* Wq    = (const float*)d_in[8];
  const float* bq    = (const float*)d_in[9];
  const float* Wk    = (const float*)d_in[10];
  const float* bk    = (const float*)d_in[11];
  const float* Wo    = (const float*)d_in[12];
  const float* bo    = (const float*)d_in[13];
  const float* Wih   = (const float*)d_in[14];
  const float* bih   = (const float*)d_in[15];
  const float* Whh   = (const float*)d_in[16];
  const float* bhh   = (const float*)d_in[17];
  const float* r1w   = (const float*)d_in[18];
  const float* r1b   = (const float*)d_in[19];
  const float* r2w   = (const float*)d_in[20];
  const float* r2b   = (const float*)d_in[21];
  const float* r3w   = (const float*)d_in[22];
  const float* r3b   = (const float*)d_in[23];
  const float* r4w   = (const float*)d_in[24];
  const float* r4b   = (const float*)d_in[25];
  float* out = (float*)d_out;

  float* ws    = (float*)d_ws;
  float* kproj = ws;                  // 4096*128 = 524288
  float* qproj = ws + 524288;         // 64*128   = 8192
  float* XW    = ws + 532480;         // 1024*128 = 131072

  k_embed_proj<<<520, 128, 0, stream>>>(
      ts, query, w_lin, b_lin, w_per, b_per, Wk, bk, Wq, bq, kproj, qproj);
  k_attn_fused<<<NB * 16, 512, 0, stream>>>(
      x, mask, qproj, kproj, Wo, bo, Wih, bih, bhh, XW);
  k_rnn<<<NB, 256, 0, stream>>>(XW, Whh, r1w, r1b, r2w, r2b, r3w, r3b,
                                r4w, r4b, out);
}

// Round 3
// 178.857 us; speedup vs baseline: 1.1105x; 1.1105x over previous
//
#include <hip/hip_runtime.h>
#include <hip/hip_bf16.h>

// All tensors are float32 (verified R2/R3: runtime dtype probe took the f32
// branch; bf16 interpretation NaN'd in R1/R4). Output float32.
//
// k_rnn floor note (R6-R12): seven structural variants of the 64-step RNN
// tie at 42-47 us. Kept verbatim.
//
// R1/R2 post-mortem: fusing all heads into 256 big blocks lost 4x block
// parallelism (1 block/CU) and never beat the R0 4-kernel structure; the
// stride-20 qq-rotation "swizzle" was bank-invariant (rotation adds
// multiples of 4 to residues already closed under +4) -> conflicts stayed.
// R3: back to 1024-block attn, but phase B reads ONE ds_read_b128 [k][qq]
// serving 4 q-rows; x read from global (L2) instead of LDS staging; mask
// bits packed ONCE into mbg by k_embed_proj's extra blocks. LDS/block
// 38 KB -> 7.4 KB. out_xw/embed switch broadcast reads to float4.

#define NB 16
#define NL 256
#define NLQ 64
#define NDIN 32
#define NET 128
#define NH 4
#define NETK 32

// Padded LDS layout for h/tmp in k_rnn (R8: conflicts -> 0).
#define HPAD 136
#define PAD(i) ((i) + 4 * ((i) >> 6))

// ---------------------------------------------------------------------------
// Kernel 1: time embedding + K/Q projection + mask-bit packing.
// grid = 512 (k-rows) + 8 (q-rows) + 16 (mask pack, one per batch) = 536
// blocks, 128 threads.
// ---------------------------------------------------------------------------
__global__ __launch_bounds__(128) void k_embed_proj(
    const float* __restrict__ ts, const float* __restrict__ query,
    const float* __restrict__ mask,
    const float* __restrict__ w_lin, const float* __restrict__ b_lin,
    const float* __restrict__ w_per, const float* __restrict__ b_per,
    const float* __restrict__ Wk, const float* __restrict__ bk,
    const float* __restrict__ Wq, const float* __restrict__ bq,
    float* __restrict__ kproj, float* __restrict__ qproj,
    unsigned* __restrict__ mbg) {
  __shared__ __align__(16) float emb[8 * NET];
  int g = blockIdx.x;
  int j = threadIdx.x;

  if (g >= 520) {  // mask pack: b = g - 520, 2 rows per thread
    int b = g - 520;
#pragma unroll
    for (int half = 0; half < 2; half++) {
      int r = j + 128 * half;
      const float4* mr4 = (const float4*)(mask + (size_t)(b * NL + r) * NDIN);
      unsigned bits = 0;
#pragma unroll
      for (int u = 0; u < 8; u++) {
        float4 m = mr4[u];
        bits |= (m.x != 0.f ? 1u : 0u) << (4 * u);
        bits |= (m.y != 0.f ? 1u : 0u) << (4 * u + 1);
        bits |= (m.z != 0.f ? 1u : 0u) << (4 * u + 2);
        bits |= (m.w != 0.f ? 1u : 0u) << (4 * u + 3);
      }
      mbg[b * NL + r] = bits;
    }
    return;
  }

  bool isQ = (g >= 512);
  int base = (isQ ? g - 512 : g) * 8;
  float wl_ = w_lin[0], bl_ = b_lin[0];
  float wp = (j > 0) ? w_per[j - 1] : 0.f;
  float bp = (j > 0) ? b_per[j - 1] : 0.f;
#pragma unroll
  for (int rr = 0; rr < 8; rr++) {
    float t = isQ ? query[base + rr] : ts[base + rr];
    emb[rr * NET + j] = (j == 0) ? (t * wl_ + bl_) : sinf(t * wp + bp);
  }
  __syncthreads();
  const float* W = isQ ? Wq : Wk;
  float bias = isQ ? bq[j] : bk[j];
  float acc[8];
#pragma unroll
  for (int rr = 0; rr < 8; rr++) acc[rr] = bias;
#pragma unroll 2
  for (int i = 0; i < NET; i += 4) {
    float w0 = W[(size_t)i * NET + j];
    float w1 = W[(size_t)(i + 1) * NET + j];
    float w2 = W[(size_t)(i + 2) * NET + j];
    float w3 = W[(size_t)(i + 3) * NET + j];
#pragma unroll
    for (int rr = 0; rr < 8; rr++) {
      float4 e4 = *(const float4*)&emb[rr * NET + i];
      acc[rr] += e4.x * w0 + e4.y * w1 + e4.z * w2 + e4.w * w3;
    }
  }
  float* dst = isQ ? qproj : kproj;
#pragma unroll
  for (int rr = 0; rr < 8; rr++) dst[(size_t)(base + rr) * NET + j] = acc[rr];
}

// ---------------------------------------------------------------------------
// Kernel 2: attention. block = (b, h, qgroup of 4). grid = 1024, 256 thr.
// LDS 7.4 KB -> 4 blocks/CU (grid = exactly 4 per CU), 16 waves/CU.
// es4[k] holds all 4 qq exps as one float4: phase B does 1 ds_read_b128 +
// 2 global loads per k for 9 FMAs. Masked softmax collapses per-channel:
// att_x = sum(e*m*x)/sum(e*m); all-masked channel => mean(x), att_m = 0.
// ---------------------------------------------------------------------------
__global__ __launch_bounds__(256) void k_attn(
    const float* __restrict__ x, const unsigned* __restrict__ mbg,
    const float* __restrict__ qproj, const float* __restrict__ kproj,
    float* __restrict__ att) {
  const float SC = 0.17677669529663687f;  // 1/sqrt(32)
  int blk = blockIdx.x;
  int qg = blk & 15;
  int h  = (blk >> 4) & 3;
  int b  = blk >> 6;
  int t  = threadIdx.x;

  __shared__ __align__(16) float es4[NL * 4];  // 4 KB: [k][qq]
  __shared__ float part[3 * 32 * 9];           // 3.4 KB: [wave-1][c][9]

  // phase A: thread t = key row k. 4 qq scores -> one float4 write.
  {
    int k = t;
    float kr[NETK];
    const float4* kp =
        (const float4*)(kproj + (size_t)(b * NL + k) * NET + h * NETK);
#pragma unroll
    for (int i = 0; i < 8; i++) {
      float4 v = kp[i];
      kr[4 * i] = v.x; kr[4 * i + 1] = v.y;
      kr[4 * i + 2] = v.z; kr[4 * i + 3] = v.w;
    }
    float ev[4];
#pragma unroll
    for (int qq = 0; qq < 4; qq++) {
      // wave-uniform address -> scalar loads through K-cache
      const float* qv = qproj + (size_t)(qg * 4 + qq) * NET + h * NETK;
      float s0 = 0.f, s1 = 0.f;
#pragma unroll
      for (int i = 0; i < NETK; i += 2) {
        s0 += qv[i] * kr[i];
        s1 += qv[i + 1] * kr[i + 1];
      }
      ev[qq] = __expf((s0 + s1) * SC);
    }
    *(float4*)&es4[k * 4] = make_float4(ev[0], ev[1], ev[2], ev[3]);
  }
  __syncthreads();

  // phase B: thread = (kq = t>>5, c = t&31), 32 k-iters each.
  int kq = t >> 5, c = t & 31;
  float den[4] = {0.f, 0.f, 0.f, 0.f};
  float num[4] = {0.f, 0.f, 0.f, 0.f};
  float sumx = 0.f;
  {
    const float* xb = x + (size_t)b * NL * NDIN;
    const unsigned* mbb = mbg + b * NL;
    int k0 = kq * 32;
#pragma unroll 4
    for (int kk = 0; kk < 32; kk++) {
      int k = k0 + kk;
      float4 e4 = *(const float4*)&es4[k * 4];
      float xv = xb[(size_t)k * NDIN + c];
      float mv = ((mbb[k] >> c) & 1u) ? 1.f : 0.f;
      sumx += xv;
      float e0 = e4.x * mv, e1 = e4.y * mv, e2 = e4.z * mv, e3 = e4.w * mv;
      den[0] += e0; num[0] += e0 * xv;
      den[1] += e1; num[1] += e1 * xv;
      den[2] += e2; num[2] += e2 * xv;
      den[3] += e3; num[3] += e3 * xv;
    }
  }
  // combine kq pairs within the wave (lane l <-> l+32 differ only in kq)
  sumx += __shfl_xor(sumx, 32, 64);
#pragma unroll
  for (int q = 0; q < 4; q++) {
    den[q] += __shfl_xor(den[q], 32, 64);
    num[q] += __shfl_xor(num[q], 32, 64);
  }
  // waves 1..3 publish partials (stride 9 -> conflict-free)
  {
    int w = t >> 6, lane = t & 63;
    if (w > 0 && lane < 32) {
      float* p = &part[((w - 1) * 32 + c) * 9];
#pragma unroll
      for (int q = 0; q < 4; q++) { p[q] = den[q]; p[4 + q] = num[q]; }
      p[8] = sumx;
    }
  }
  __syncthreads();

  // wave 0 lanes 0-31 combine + finalize
  if (t < 32) {
#pragma unroll
    for (int ww = 0; ww < 3; ww++) {
      const float* p = &part[(ww * 32 + t) * 9];
#pragma unroll
      for (int q = 0; q < 4; q++) { den[q] += p[q]; num[q] += p[4 + q]; }
      sumx += p[8];
    }
    float meanx = sumx * (1.f / 256.f);
#pragma unroll
    for (int qq = 0; qq < 4; qq++) {
      bool any = (den[qq] > 0.f);
      float* ao =
          att + (size_t)(((b * NLQ + qg * 4 + qq) * NH) + h) * 64;
      ao[t]      = any ? (num[qq] / den[qq]) : meanx;
      ao[32 + t] = any ? 1.f : 0.f;
    }
  }
}

// ---------------------------------------------------------------------------
// Kernel 3: out = att @ Wo + bo; XW = out @ W_ih + b_ih + b_hh.
// grid = B*LQ = 1024 blocks, 128 threads. Broadcast reads via float4.
// ---------------------------------------------------------------------------
__global__ __launch_bounds__(128) void k_out_xw(
    const float* __restrict__ att,
    const float* __restrict__ Wo, const float* __restrict__ bo,
    const float* __restrict__ Wih, const float* __restrict__ bih,
    const float* __restrict__ bhh, float* __restrict__ XW) {
  int r = blockIdx.x;
  int j = threadIdx.x;
  __shared__ __align__(16) float arow[NH * 64];
  __shared__ __align__(16) float orow[NET];
  arow[j]       = att[(size_t)r * 256 + j];
  arow[j + 128] = att[(size_t)r * 256 + 128 + j];
  __syncthreads();
  float a0 = bo[j], a1 = 0.f, a2 = 0.f, a3 = 0.f;
#pragma unroll 4
  for (int u = 0; u < 256; u += 4) {
    float4 av = *(const float4*)&arow[u];
    a0 += av.x * Wo[(size_t)u * NET + j];
    a1 += av.y * Wo[(size_t)(u + 1) * NET + j];
    a2 += av.z * Wo[(size_t)(u + 2) * NET + j];
    a3 += av.w * Wo[(size_t)(u + 3) * NET + j];
  }
  orow[j] = (a0 + a1) + (a2 + a3);
  __syncthreads();
  float b0 = bih[j] + bhh[j], b1 = 0.f, b2 = 0.f, b3 = 0.f;
#pragma unroll 4
  for (int e = 0; e < NET; e += 4) {
    float4 ov = *(const float4*)&orow[e];
    b0 += ov.x * Wih[(size_t)e * NET + j];
    b1 += ov.y * Wih[(size_t)(e + 1) * NET + j];
    b2 += ov.z * Wih[(size_t)(e + 2) * NET + j];
    b3 += ov.w * Wih[(size_t)(e + 3) * NET + j];
  }
  XW[(size_t)r * NET + j] = (b0 + b1) + (b2 + b3);
}

// ---------------------------------------------------------------------------
// helper: dst[PAD(j)] = b[j] + sum_i src[i] * W[i*128+j], split-2 over s.
// ---------------------------------------------------------------------------
__device__ __forceinline__ void layer128(const float* src_lds,
                                         const float* __restrict__ W,
                                         const float* __restrict__ bvec,
                                         float* dst_lds, int j, int s) {
  const float4* h4 = (const float4*)(src_lds + s * 68);
  float a0 = 0.f, a1 = 0.f, a2 = 0.f, a3 = 0.f;
#pragma unroll
  for (int i = 0; i < 16; i++) {
    float4 hv = h4[i];
    int base = (s * 64 + 4 * i) * NET + j;
    a0 += hv.x * W[base];
    a1 += hv.y * W[base + NET];
    a2 += hv.z * W[base + 2 * NET];
    a3 += hv.w * W[base + 3 * NET];
  }
  float acc = (a0 + a1) + (a2 + a3);
  acc += __shfl_xor(acc, 1, 64);
  if (s == 0) dst_lds[PAD(j)] = acc + bvec[j];
}

// ---------------------------------------------------------------------------
// Kernel 4: sequential RNN (64 steps) + regressor. grid = 16, 256 threads.
// Kept verbatim (measured floor ~42 us).
// ---------------------------------------------------------------------------
__global__ __launch_bounds__(256, 1) void k_rnn(
    const float* __restrict__ XW, const float* __restrict__ Whh,
    const float* __restrict__ r1w, const float* __restrict__ r1b,
    const float* __restrict__ r2w, const float* __restrict__ r2b,
    const float* __restrict__ r3w, const float* __restrict__ r3b,
    const float* __restrict__ r4w, const float* __restrict__ r4b,
    float* __restrict__ out) {
  int b = blockIdx.x;
  int tid = threadIdx.x;
  int s = tid & 1;
  int j = tid >> 1;
  __shared__ float xwl[NLQ * NET];  // 32 KB, staged once
  __shared__ float hb[2][HPAD];
  __shared__ float tmp[HPAD];

  {
    const float4* src = (const float4*)(XW + (size_t)b * NLQ * NET);
    float4* dst = (float4*)xwl;
#pragma unroll
    for (int u = 0; u < 8; u++) dst[tid + 256 * u] = src[tid + 256 * u];
  }
  float w[64];
#pragma unroll
  for (int i = 0; i < 64; i++) w[i] = Whh[(s * 64 + i) * NET + j];

  if (tid < 128) hb[0][PAD(tid)] = 0.f;
  __syncthreads();

  for (int t = 0; t < NLQ; t++) {
    float xwv = xwl[t * NET + j];
    const float4* h4 = (const float4*)&hb[t & 1][s * 68];
    float a0 = 0.f, a1 = 0.f, a2 = 0.f, a3 = 0.f;
#pragma unroll
    for (int i = 0; i < 16; i++) {
      float4 hv = h4[i];
      a0 += hv.x * w[4 * i];
      a1 += hv.y * w[4 * i + 1];
      a2 += hv.z * w[4 * i + 2];
      a3 += hv.w * w[4 * i + 3];
    }
    float acc = (a0 + a1) + (a2 + a3);
    acc += __shfl_xor(acc, 1, 64);
    if (s == 0) {
      float z = acc + xwv;
      float e2 = __expf(2.f * z);
      hb[(t + 1) & 1][PAD(j)] = 1.f - 2.f / (e2 + 1.f);  // tanh(z)
    }
    __syncthreads();
  }

  layer128(hb[0], r1w, r1b, tmp, j, s);
  __syncthreads();
  layer128(tmp, r2w, r2b, hb[1], j, s);
  __syncthreads();
  layer128(hb[1], r3w, r3b, hb[0], j, s);
  __syncthreads();
  if (tid < 64) {
    int jj = tid >> 3, p = tid & 7;
    float y = 0.f;
#pragma unroll
    for (int i = 0; i < 16; i++) {
      int ii = p * 16 + i;
      y += hb[0][PAD(ii)] * r4w[ii * 8 + jj];
    }
    y += __shfl_xor(y, 1, 64);
    y += __shfl_xor(y, 2, 64);
    y += __shfl_xor(y, 4, 64);
    if (p == 0) out[b * 8 + jj] = y + r4b[jj];
  }
}

// ---------------------------------------------------------------------------
extern "C" void kernel_launch(void* const* d_in, const int* in_sizes, int n_in,
                              void* d_out, int out_size, void* d_ws, size_t ws_size,
                              hipStream_t stream) {
  const float* x     = (const float*)d_in[0];
  const float* ts    = (const float*)d_in[1];
  const float* mask  = (const float*)d_in[2];
  const float* query = (const float*)d_in[3];
  const float* w_lin = (const float*)d_in[4];
  const float* b_lin = (const float*)d_in[5];
  const float* w_per = (const float*)d_in[6];
  const float* b_per = (const float*)d_in[7];
  const float* Wq    = (const float*)d_in[8];
  const float* bq    = (const float*)d_in[9];
  const float* Wk    = (const float*)d_in[10];
  const float* bk    = (const float*)d_in[11];
  const float* Wo    = (const float*)d_in[12];
  const float* bo    = (const float*)d_in[13];
  const float* Wih   = (const float*)d_in[14];
  const float* bih   = (const float*)d_in[15];
  const float* Whh   = (const float*)d_in[16];
  const float* bhh   = (const float*)d_in[17];
  const float* r1w   = (const float*)d_in[18];
  const float* r1b   = (const float*)d_in[19];
  const float* r2w   = (const float*)d_in[20];
  const float* r2b   = (const float*)d_in[21];
  const float* r3w   = (const float*)d_in[22];
  const float* r3b   = (const float*)d_in[23];
  const float* r4w   = (const float*)d_in[24];
  const float* r4b   = (const float*)d_in[25];
  float* out = (float*)d_out;

  float* ws    = (float*)d_ws;
  float* kproj = ws;                  // 4096*128 = 524288
  float* qproj = ws + 524288;         // 64*128   = 8192
  float* att   = ws + 532480;         // 1024*256 = 262144
  float* XW    = ws + 794624;         // 1024*128 = 131072
  unsigned* mbg = (unsigned*)(ws + 925696);  // 4096 u32 = 16 KB

  k_embed_proj<<<536, 128, 0, stream>>>(
      ts, query, mask, w_lin, b_lin, w_per, b_per, Wk, bk, Wq, bq,
      kproj, qproj, mbg);
  k_attn<<<NB * NH * 16, 256, 0, stream>>>(x, mbg, qproj, kproj, att);
  k_out_xw<<<NB * NLQ, 128, 0, stream>>>(att, Wo, bo, Wih, bih, bhh, XW);
  k_rnn<<<NB, 256, 0, stream>>>(XW, Whh, r1w, r1b, r2w, r2b, r3w, r3b,
                                r4w, r4b, out);
}